// Round 2
// baseline (2010.390 us; speedup 1.0000x reference)
//
#include <hip/hip_runtime.h>
#include <hip/hip_bf16.h>
#include <stdint.h>

#define DEVI static __device__ __forceinline__

typedef __bf16 bf16x8 __attribute__((ext_vector_type(8)));
typedef float f32x4 __attribute__((ext_vector_type(4)));
typedef int   int4v __attribute__((ext_vector_type(4)));

DEVI float bf2f(uint16_t u){ uint32_t x = ((uint32_t)u) << 16; float f; __builtin_memcpy(&f, &x, 4); return f; }
DEVI uint16_t f2bf(float f){ uint32_t u; __builtin_memcpy(&u, &f, 4); uint32_t r = (u + 0x7FFFu + ((u >> 16) & 1u)) >> 16; return (uint16_t)r; }
DEVI float frcp(float x){ return __builtin_amdgcn_rcpf(x); }
DEVI float sigm(float x){ return frcp(1.f + __expf(-x)); }
DEVI float tanhfast(float x){ return 1.f - 2.f * frcp(1.f + __expf(2.f * x)); }
DEVI f32x4 mfma16(bf16x8 a, bf16x8 b, f32x4 c){ return __builtin_amdgcn_mfma_f32_16x16x32_bf16(a, b, c, 0, 0, 0); }

// load 8 consecutive f32, round to bf16x8
DEVI bf16x8 cvt8(const float* __restrict__ p){
    f32x4 a = *(const f32x4*)p, b = *(const f32x4*)(p + 4);
    union { bf16x8 v; uint16_t u[8]; } r;
    #pragma unroll
    for (int e = 0; e < 4; ++e) { r.u[e] = f2bf(a[e]); r.u[4 + e] = f2bf(b[e]); }
    return r.v;
}
DEVI int4v asint4(bf16x8 v){ int4v r; __builtin_memcpy(&r, &v, 16); return r; }

// ---------------------------------------------------------------------------
// Kernel 1: input projection (B*L,64)@(64,256) + bias + ReLU + LayerNorm -> Y bf16
// block = 256 thr (4 waves), 64 rows/block. grid = 1024.
// ---------------------------------------------------------------------------
__global__ __launch_bounds__(256) void k_inproj(
    const float* __restrict__ X, const float* __restrict__ W,
    const float* __restrict__ bias, const float* __restrict__ g,
    const float* __restrict__ beta, uint16_t* __restrict__ Y)
{
    __shared__ __align__(16) char As[64 * 128];   // 64 rows x 64 bf16 (swizzled)
    __shared__ __align__(16) char Bs[256 * 128];  // 256 rows(n) x 64 bf16 (swizzled)
    const int tid = threadIdx.x;
    const long rowbase = (long)blockIdx.x * 64;

    #pragma unroll
    for (int it = 0; it < 2; ++it) {
        int c = it * 256 + tid; int r = c >> 3, cc = c & 7;
        bf16x8 v = cvt8(X + (rowbase + r) * 64 + cc * 8);
        *(int4v*)(As + r * 128 + ((cc * 16) ^ ((r & 7) << 4))) = asint4(v);
    }
    #pragma unroll
    for (int it = 0; it < 8; ++it) {
        int c = it * 256 + tid; int r = c >> 3, cc = c & 7;
        bf16x8 v = cvt8(W + r * 64 + cc * 8);
        *(int4v*)(Bs + r * 128 + ((cc * 16) ^ ((r & 7) << 4))) = asint4(v);
    }
    __syncthreads();

    const int w = tid >> 6, l = tid & 63, lr = l & 15, lg = l >> 4;
    f32x4 acc[16];
    #pragma unroll
    for (int i = 0; i < 16; ++i) acc[i] = (f32x4){0.f, 0.f, 0.f, 0.f};
    const int arow = w * 16 + lr;
    #pragma unroll
    for (int ks = 0; ks < 2; ++ks) {
        bf16x8 a = *(bf16x8*)(As + arow * 128 + ((ks * 64 + lg * 16) ^ ((arow & 7) << 4)));
        #pragma unroll
        for (int tl = 0; tl < 16; ++tl) {
            int n = tl * 16 + lr;
            bf16x8 b = *(bf16x8*)(Bs + n * 128 + ((ks * 64 + lg * 16) ^ ((n & 7) << 4)));
            acc[tl] = mfma16(a, b, acc[tl]);
        }
    }
    float gv[16], bv[16], biasv[16];
    #pragma unroll
    for (int tl = 0; tl < 16; ++tl) {
        int col = tl * 16 + lr;
        gv[tl] = g[col]; bv[tl] = beta[col]; biasv[tl] = bias[col];
    }
    #pragma unroll
    for (int i = 0; i < 4; ++i) {
        float s = 0.f, sq = 0.f, v[16];
        #pragma unroll
        for (int tl = 0; tl < 16; ++tl) {
            float xv = acc[tl][i] + biasv[tl]; xv = fmaxf(xv, 0.f);
            v[tl] = xv; s += xv; sq += xv * xv;
        }
        #pragma unroll
        for (int d = 1; d < 16; d <<= 1) { s += __shfl_xor(s, d); sq += __shfl_xor(sq, d); }
        float mean = s * (1.f / 256.f);
        float var  = sq * (1.f / 256.f) - mean * mean;
        float sc   = rsqrtf(var + 1e-5f);
        long row = rowbase + w * 16 + lg * 4 + i;
        #pragma unroll
        for (int tl = 0; tl < 16; ++tl)
            Y[row * 256 + tl * 16 + lr] = f2bf((v[tl] - mean) * sc * gv[tl] + bv[tl]);
    }
}

// ---------------------------------------------------------------------------
// Kernel 2: input-gate GEMM  XG = A(65536,KIN) @ W(768,KIN)^T + bias  -> bf16
// A is internal bf16 (!ZBUILD) or built from z (f32) + 0.05*noise (f32).
// W/bias are f32 (model params). block 256 thr: 64 rows x 192 cols. grid (1024,4).
// ---------------------------------------------------------------------------
template<int KIN, bool ZBUILD>
__global__ __launch_bounds__(256) void k_xg(
    const uint16_t* __restrict__ A, const float* __restrict__ W,
    const float* __restrict__ bias, uint16_t* __restrict__ XG,
    const float* __restrict__ zbuf, const float* __restrict__ noise)
{
    constexpr int KB = KIN * 2;           // row bytes (bf16)
    constexpr int KS = KIN / 32;          // mfma k-steps
    constexpr int CPR = KB / 16;          // 16B chunks per row
    __shared__ __align__(16) char As[64 * KB];
    __shared__ __align__(16) char Bs[192 * KB];
    const int tid = threadIdx.x;
    const long rowbase = (long)blockIdx.x * 64;
    const int nb = blockIdx.y;

    #pragma unroll
    for (int it = 0; it < (64 * CPR) / 256; ++it) {
        int c = it * 256 + tid; int r = c / CPR, cc = c % CPR;
        if constexpr (!ZBUILD) {
            int4v v = *(const int4v*)(A + (rowbase + r) * KIN + cc * 8);
            *(int4v*)(As + r * KB + ((cc * 16) ^ ((r & 7) << 4))) = v;
        } else {
            long rg = rowbase + r; int b = (int)(rg >> 7);
            const float* zr = zbuf + b * 64 + cc * 8;
            const float* nr = noise + rg * 64 + cc * 8;
            f32x4 z0 = *(const f32x4*)zr, z1 = *(const f32x4*)(zr + 4);
            f32x4 n0 = *(const f32x4*)nr, n1 = *(const f32x4*)(nr + 4);
            union { int4v v; uint16_t u[8]; } un;
            #pragma unroll
            for (int e = 0; e < 4; ++e) {
                un.u[e]     = f2bf(z0[e] + 0.05f * n0[e]);
                un.u[4 + e] = f2bf(z1[e] + 0.05f * n1[e]);
            }
            *(int4v*)(As + r * KB + ((cc * 16) ^ ((r & 7) << 4))) = un.v;
        }
    }
    #pragma unroll
    for (int it = 0; it < (192 * CPR) / 256; ++it) {
        int c = it * 256 + tid; int r = c / CPR, cc = c % CPR;
        bf16x8 v = cvt8(W + (long)(nb * 192 + r) * KIN + cc * 8);
        *(int4v*)(Bs + r * KB + ((cc * 16) ^ ((r & 7) << 4))) = asint4(v);
    }
    __syncthreads();

    const int w = tid >> 6, l = tid & 63, lr = l & 15, lg = l >> 4;
    f32x4 acc[12];
    #pragma unroll
    for (int i = 0; i < 12; ++i) acc[i] = (f32x4){0.f, 0.f, 0.f, 0.f};
    const int arow = w * 16 + lr;
    #pragma unroll
    for (int ks = 0; ks < KS; ++ks) {
        bf16x8 a = *(bf16x8*)(As + arow * KB + ((ks * 64 + lg * 16) ^ ((arow & 7) << 4)));
        #pragma unroll
        for (int tl = 0; tl < 12; ++tl) {
            int n = tl * 16 + lr;
            bf16x8 b = *(bf16x8*)(Bs + n * KB + ((ks * 64 + lg * 16) ^ ((n & 7) << 4)));
            acc[tl] = mfma16(a, b, acc[tl]);
        }
    }
    #pragma unroll
    for (int tl = 0; tl < 12; ++tl) {
        int colg = nb * 192 + tl * 16 + lr;
        float bs = bias[colg];
        #pragma unroll
        for (int i = 0; i < 4; ++i) {
            long row = rowbase + w * 16 + lg * 4 + i;
            XG[row * 768 + colg] = f2bf(acc[tl][i] + bs);
        }
    }
}

// ---------------------------------------------------------------------------
// Kernel 3: persistent GRU layer. grid = 32 blocks x 512 thr (8 waves).
// Block owns 16 batch rows; wave owns 32 h-cols (6 N-tiles over r/z/n gates).
// Whh K in [0,192) register-resident; K in [192,256) in LDS (bf16-converted).
// Hidden state fp32 in registers; bf16 copy in LDS for MFMA A-operand.
// ---------------------------------------------------------------------------
__global__ __launch_bounds__(512) void k_gru(
    const uint16_t* __restrict__ XG, const float* __restrict__ Whh,
    const float* __restrict__ bhh, uint16_t* __restrict__ Y,
    float* __restrict__ hlast)
{
    constexpr int L = 128;
    constexpr int XROW = 1552;                       // padded bytes per xg row
    __shared__ __align__(16) char Abuf[16 * 512];    // h bf16, swizzled
    __shared__ __align__(16) char Wt[768 * 128];     // Whh K-tail, swizzled
    __shared__ __align__(16) char Xb[2][16 * XROW];  // staged xg double-buffer
    const int tid = threadIdx.x;
    const int w = tid >> 6, l = tid & 63, lr = l & 15, lg = l >> 4;
    const long rowg0 = (long)blockIdx.x * 16;

    for (int i = tid; i < 16 * 512 / 4; i += 512) ((uint32_t*)Abuf)[i] = 0;

    #pragma unroll
    for (int it = 0; it < 12; ++it) {                // stage Whh K-tail (f32 -> bf16)
        int c = it * 512 + tid; int r = c >> 3, cc = c & 7;
        bf16x8 v = cvt8(Whh + r * 256 + 192 + cc * 8);
        *(int4v*)(Wt + r * 128 + ((cc * 16) ^ ((r & 7) << 4))) = asint4(v);
    }

    int gb[6];
    #pragma unroll
    for (int tl = 0; tl < 6; ++tl) gb[tl] = (tl >> 1) * 256 + w * 32 + (tl & 1) * 16;
    bf16x8 wf[6][6];
    #pragma unroll
    for (int tl = 0; tl < 6; ++tl) {
        int n = gb[tl] + lr;
        #pragma unroll
        for (int ks = 0; ks < 6; ++ks)
            wf[tl][ks] = cvt8(Whh + n * 256 + ks * 32 + lg * 8);
    }
    float bh[6];
    #pragma unroll
    for (int tl = 0; tl < 6; ++tl) bh[tl] = bhh[gb[tl] + lr];

    // stage xg(t=0)
    const int pr = tid >> 5, pc = tid & 31;
    {
        const uint16_t* src = XG + ((rowg0 + pr) * L + 0) * 768 + pc * 24;
        char* dst = Xb[0] + pr * XROW + pc * 48;
        *(int4v*)dst        = *(const int4v*)(src);
        *(int4v*)(dst + 16) = *(const int4v*)(src + 8);
        *(int4v*)(dst + 32) = *(const int4v*)(src + 16);
    }
    float hreg[2][4] = {{0.f,0.f,0.f,0.f},{0.f,0.f,0.f,0.f}};
    const bool wy = (Y != nullptr);
    __syncthreads();

    for (int t = 0; t < L; ++t) {
        int4v gx0, gx1, gx2;
        if (t + 1 < L) {                             // prefetch next xg tile
            const uint16_t* src = XG + ((rowg0 + pr) * L + (t + 1)) * 768 + pc * 24;
            gx0 = *(const int4v*)(src);
            gx1 = *(const int4v*)(src + 8);
            gx2 = *(const int4v*)(src + 16);
        }
        f32x4 acc[6];
        #pragma unroll
        for (int i = 0; i < 6; ++i) acc[i] = (f32x4){0.f, 0.f, 0.f, 0.f};
        #pragma unroll
        for (int ks = 0; ks < 8; ++ks) {
            bf16x8 a = *(bf16x8*)(Abuf + lr * 512 + ((ks * 64 + lg * 16) ^ ((lr & 7) << 4)));
            if (ks < 6) {
                #pragma unroll
                for (int tl = 0; tl < 6; ++tl) acc[tl] = mfma16(a, wf[tl][ks], acc[tl]);
            } else {
                #pragma unroll
                for (int tl = 0; tl < 6; ++tl) {
                    int n = gb[tl] + lr;
                    bf16x8 b = *(bf16x8*)(Wt + n * 128 + (((ks - 6) * 64 + lg * 16) ^ ((n & 7) << 4)));
                    acc[tl] = mfma16(a, b, acc[tl]);
                }
            }
        }
        __syncthreads();   // all A-reads done; safe to write h_{t+1}

        const char* xb = Xb[t & 1];
        #pragma unroll
        for (int sub = 0; sub < 2; ++sub) {
            #pragma unroll
            for (int i = 0; i < 4; ++i) {
                int row = lg * 4 + i;
                int colr = w * 32 + sub * 16 + lr;
                float xr = bf2f(*(const uint16_t*)(xb + row * XROW + (colr)       * 2));
                float xz = bf2f(*(const uint16_t*)(xb + row * XROW + (256 + colr) * 2));
                float xn = bf2f(*(const uint16_t*)(xb + row * XROW + (512 + colr) * 2));
                float rg_ = sigm(xr + acc[0 + sub][i] + bh[0 + sub]);
                float zg  = sigm(xz + acc[2 + sub][i] + bh[2 + sub]);
                float nn  = tanhfast(xn + rg_ * (acc[4 + sub][i] + bh[4 + sub]));
                float h = hreg[sub][i];
                h = nn + zg * (h - nn);
                hreg[sub][i] = h;
                uint16_t hb = f2bf(h);
                *(uint16_t*)(Abuf + row * 512 + (((colr * 2) & ~15) ^ ((row & 7) << 4)) + ((colr * 2) & 15)) = hb;
                if (wy) Y[((rowg0 + row) * L + t) * 256 + colr] = hb;
            }
        }
        if (t + 1 < L) {
            char* dst = Xb[(t + 1) & 1] + pr * XROW + pc * 48;
            *(int4v*)dst = gx0; *(int4v*)(dst + 16) = gx1; *(int4v*)(dst + 32) = gx2;
        }
        __syncthreads();   // h_{t+1} and xg_{t+1} visible
    }
    if (hlast) {
        #pragma unroll
        for (int sub = 0; sub < 2; ++sub)
            #pragma unroll
            for (int i = 0; i < 4; ++i) {
                int row = lg * 4 + i, colr = w * 32 + sub * 16 + lr;
                hlast[(rowg0 + row) * 256 + colr] = hreg[sub][i];
            }
    }
}

// ---------------------------------------------------------------------------
// Kernel 4: mu / log_var / z.  grid = 256 blocks x 256 thr, 2 rows/block.
// ---------------------------------------------------------------------------
__global__ __launch_bounds__(256) void k_z(
    const float* __restrict__ hlast, const float* __restrict__ muW,
    const float* __restrict__ mub, const float* __restrict__ lvW,
    const float* __restrict__ lvb, const float* __restrict__ eps,
    float* __restrict__ mu_out, float* __restrict__ lv_out,
    float* __restrict__ zout)
{
    __shared__ float hrow[2][256];
    __shared__ float res[2][128];
    const int tid = threadIdx.x;
    const long row0 = (long)blockIdx.x * 2;
    for (int i = tid; i < 512; i += 256) ((float*)hrow)[i] = hlast[row0 * 256 + i];
    __syncthreads();
    const int lrr = tid >> 7, c = tid & 127;
    const float* Wr = (c < 64 ? muW : lvW) + (long)(c & 63) * 256;
    float acc = (c < 64) ? mub[c] : lvb[c & 63];
    const float* hr = hrow[lrr];
    #pragma unroll 8
    for (int k = 0; k < 256; k += 4) {
        f32x4 wv = *(const f32x4*)(Wr + k);
        #pragma unroll
        for (int e = 0; e < 4; ++e) acc += hr[k + e] * wv[e];
    }
    res[lrr][c] = acc;
    long row = row0 + lrr;
    if (c < 64) mu_out[row * 64 + c] = acc;
    else        lv_out[row * 64 + (c & 63)] = acc;
    __syncthreads();
    if (c < 64) {
        float m = res[lrr][c], lv = res[lrr][64 + c];
        zout[row * 64 + c] = m + eps[row * 64 + c] * __expf(0.5f * lv);
    }
}

// ---------------------------------------------------------------------------
// Kernel 5: post proj + ReLU + LN, then output proj + tanh -> x_hat (f32).
// block 256 thr (4 waves), 64 rows/block. grid = 1024.
// ---------------------------------------------------------------------------
__global__ __launch_bounds__(256) void k_post(
    const uint16_t* __restrict__ D1, const float* __restrict__ pW,
    const float* __restrict__ pb, const float* __restrict__ pg,
    const float* __restrict__ pbeta, const float* __restrict__ oW,
    const float* __restrict__ ob, float* __restrict__ xhat)
{
    __shared__ __align__(16) char Bs[256 * 512];  // post_W bf16 staged (reused for d_ln)
    const int tid = threadIdx.x;
    const long rowbase = (long)blockIdx.x * 64;
    #pragma unroll
    for (int it = 0; it < 32; ++it) {
        int c = it * 256 + tid; int r = c >> 5, cc = c & 31;
        bf16x8 v = cvt8(pW + r * 256 + cc * 8);
        *(int4v*)(Bs + r * 512 + ((cc * 16) ^ ((r & 7) << 4))) = asint4(v);
    }
    __syncthreads();
    const int w = tid >> 6, l = tid & 63, lr = l & 15, lg = l >> 4;
    const long arow = rowbase + w * 16 + lr;
    bf16x8 af[8];
    #pragma unroll
    for (int ks = 0; ks < 8; ++ks) af[ks] = *(const bf16x8*)(D1 + arow * 256 + ks * 32 + lg * 8);
    f32x4 acc[16];
    #pragma unroll
    for (int i = 0; i < 16; ++i) acc[i] = (f32x4){0.f, 0.f, 0.f, 0.f};
    #pragma unroll
    for (int ks = 0; ks < 8; ++ks) {
        #pragma unroll
        for (int tl = 0; tl < 16; ++tl) {
            int n = tl * 16 + lr;
            bf16x8 b = *(bf16x8*)(Bs + n * 512 + ((ks * 64 + lg * 16) ^ ((n & 7) << 4)));
            acc[tl] = mfma16(af[ks], b, acc[tl]);
        }
    }
    float gv[16], bv[16], biasv[16];
    #pragma unroll
    for (int tl = 0; tl < 16; ++tl) {
        int col = tl * 16 + lr;
        gv[tl] = pg[col]; bv[tl] = pbeta[col]; biasv[tl] = pb[col];
    }
    uint16_t dl[16][4];
    #pragma unroll
    for (int i = 0; i < 4; ++i) {
        float s = 0.f, sq = 0.f, v[16];
        #pragma unroll
        for (int tl = 0; tl < 16; ++tl) {
            float xv = acc[tl][i] + biasv[tl]; xv = fmaxf(xv, 0.f);
            v[tl] = xv; s += xv; sq += xv * xv;
        }
        #pragma unroll
        for (int d = 1; d < 16; d <<= 1) { s += __shfl_xor(s, d); sq += __shfl_xor(sq, d); }
        float mean = s * (1.f / 256.f);
        float var  = sq * (1.f / 256.f) - mean * mean;
        float sc   = rsqrtf(var + 1e-5f);
        #pragma unroll
        for (int tl = 0; tl < 16; ++tl)
            dl[tl][i] = f2bf((v[tl] - mean) * sc * gv[tl] + bv[tl]);
    }
    __syncthreads();   // done reading post_W from Bs
    #pragma unroll
    for (int tl = 0; tl < 16; ++tl) {
        int col = tl * 16 + lr;
        #pragma unroll
        for (int i = 0; i < 4; ++i) {
            int row = w * 16 + lg * 4 + i;
            *(uint16_t*)(Bs + row * 512 + (((col * 2) & ~15) ^ ((row & 7) << 4)) + ((col * 2) & 15)) = dl[tl][i];
        }
    }
    __syncthreads();
    const int ar2 = w * 16 + lr;
    f32x4 acc2[4];
    #pragma unroll
    for (int i = 0; i < 4; ++i) acc2[i] = (f32x4){0.f, 0.f, 0.f, 0.f};
    #pragma unroll
    for (int ks = 0; ks < 8; ++ks) {
        bf16x8 a = *(bf16x8*)(Bs + ar2 * 512 + ((ks * 64 + lg * 16) ^ ((ar2 & 7) << 4)));
        #pragma unroll
        for (int tl = 0; tl < 4; ++tl) {
            int n = tl * 16 + lr;
            bf16x8 b = cvt8(oW + n * 256 + ks * 32 + lg * 8);
            acc2[tl] = mfma16(a, b, acc2[tl]);
        }
    }
    #pragma unroll
    for (int tl = 0; tl < 4; ++tl) {
        int col = tl * 16 + lr;
        float bo = ob[col];
        #pragma unroll
        for (int i = 0; i < 4; ++i) {
            long row = rowbase + w * 16 + lg * 4 + i;
            xhat[row * 64 + col] = tanhfast(acc2[tl][i] + bo);
        }
    }
}

// ---------------------------------------------------------------------------
extern "C" void kernel_launch(void* const* d_in, const int* in_sizes, int n_in,
                              void* d_out, int out_size, void* d_ws, size_t ws_size,
                              hipStream_t stream)
{
    (void)in_sizes; (void)n_in; (void)out_size; (void)ws_size;
    const float* x     = (const float*)d_in[0];
    const float* eps   = (const float*)d_in[1];
    const float* dnz   = (const float*)d_in[2];
    const float* in_W  = (const float*)d_in[3];
    const float* in_b  = (const float*)d_in[4];
    const float* in_g  = (const float*)d_in[5];
    const float* in_be = (const float*)d_in[6];
    const float* eW0i  = (const float*)d_in[7];
    const float* eW0h  = (const float*)d_in[8];
    const float* eb0i  = (const float*)d_in[9];
    const float* eb0h  = (const float*)d_in[10];
    const float* eW1i  = (const float*)d_in[11];
    const float* eW1h  = (const float*)d_in[12];
    const float* eb1i  = (const float*)d_in[13];
    const float* eb1h  = (const float*)d_in[14];
    const float* mu_W  = (const float*)d_in[15];
    const float* mu_b  = (const float*)d_in[16];
    const float* lv_W  = (const float*)d_in[17];
    const float* lv_b  = (const float*)d_in[18];
    const float* dW0i  = (const float*)d_in[19];
    const float* dW0h  = (const float*)d_in[20];
    const float* db0i  = (const float*)d_in[21];
    const float* db0h  = (const float*)d_in[22];
    const float* dW1i  = (const float*)d_in[23];
    const float* dW1h  = (const float*)d_in[24];
    const float* db1i  = (const float*)d_in[25];
    const float* db1h  = (const float*)d_in[26];
    const float* postW = (const float*)d_in[27];
    const float* postb = (const float*)d_in[28];
    const float* postg = (const float*)d_in[29];
    const float* postbe= (const float*)d_in[30];
    const float* outW  = (const float*)d_in[31];
    const float* outb  = (const float*)d_in[32];

    char* ws = (char*)d_ws;
    uint16_t* XG   = (uint16_t*)(ws);                 // 65536*768*2 = 100663296 B
    uint16_t* YA   = (uint16_t*)(ws + 100663296);     // 65536*256*2 = 33554432 B
    uint16_t* YB   = (uint16_t*)(ws + 134217728);     // 33554432 B
    float*    hlast= (float*)   (ws + 167772160);     // 512*256*4 = 524288 B
    float*    zbuf = (float*)   (ws + 168296448);     // 512*64*4 = 131072 B

    float* out    = (float*)d_out;
    float* mu_out = out + 4194304;
    float* lv_out = out + 4194304 + 32768;

    dim3 b256(256), b512(512);

    k_inproj<<<1024, b256, 0, stream>>>(x, in_W, in_b, in_g, in_be, YA);
    k_xg<256,false><<<dim3(1024,4), b256, 0, stream>>>(YA, eW0i, eb0i, XG, nullptr, nullptr);
    k_gru<<<32, b512, 0, stream>>>(XG, eW0h, eb0h, YB, nullptr);
    k_xg<256,false><<<dim3(1024,4), b256, 0, stream>>>(YB, eW1i, eb1i, XG, nullptr, nullptr);
    k_gru<<<32, b512, 0, stream>>>(XG, eW1h, eb1h, nullptr, hlast);
    k_z<<<256, b256, 0, stream>>>(hlast, mu_W, mu_b, lv_W, lv_b, eps, mu_out, lv_out, zbuf);
    k_xg<64,true><<<dim3(1024,4), b256, 0, stream>>>(nullptr, dW0i, db0i, XG, zbuf, dnz);
    k_gru<<<32, b512, 0, stream>>>(XG, dW0h, db0h, YA, nullptr);
    k_xg<256,false><<<dim3(1024,4), b256, 0, stream>>>(YA, dW1i, db1i, XG, nullptr, nullptr);
    k_gru<<<32, b512, 0, stream>>>(XG, dW1h, db1h, YB, nullptr);
    k_post<<<1024, b256, 0, stream>>>(YB, postW, postb, postg, postbe, outW, outb, out);
}

// Round 3
// 1935.243 us; speedup vs baseline: 1.0388x; 1.0388x over previous
//
#include <hip/hip_runtime.h>
#include <hip/hip_bf16.h>
#include <stdint.h>

#define DEVI static __device__ __forceinline__

typedef __bf16 bf16x8 __attribute__((ext_vector_type(8)));
typedef float f32x4 __attribute__((ext_vector_type(4)));
typedef int   int4v __attribute__((ext_vector_type(4)));

DEVI float bf2f(uint16_t u){ uint32_t x = ((uint32_t)u) << 16; float f; __builtin_memcpy(&f, &x, 4); return f; }
DEVI uint16_t f2bf(float f){ uint32_t u; __builtin_memcpy(&u, &f, 4); uint32_t r = (u + 0x7FFFu + ((u >> 16) & 1u)) >> 16; return (uint16_t)r; }
DEVI float frcp(float x){ return __builtin_amdgcn_rcpf(x); }
DEVI float sigm(float x){ return frcp(1.f + __expf(-x)); }
DEVI float tanhfast(float x){ return 1.f - 2.f * frcp(1.f + __expf(2.f * x)); }
DEVI f32x4 mfma16(bf16x8 a, bf16x8 b, f32x4 c){ return __builtin_amdgcn_mfma_f32_16x16x32_bf16(a, b, c, 0, 0, 0); }

DEVI bf16x8 cvt8(const float* __restrict__ p){
    f32x4 a = *(const f32x4*)p, b = *(const f32x4*)(p + 4);
    union { bf16x8 v; uint16_t u[8]; } r;
    #pragma unroll
    for (int e = 0; e < 4; ++e) { r.u[e] = f2bf(a[e]); r.u[4 + e] = f2bf(b[e]); }
    return r.v;
}
DEVI int4v asint4(bf16x8 v){ int4v r; __builtin_memcpy(&r, &v, 16); return r; }

// raw barrier: lgkm drain only (no vmcnt drain — stores/prefetch stay in flight)
DEVI void bar_lds(){
    asm volatile("s_waitcnt lgkmcnt(0)" ::: "memory");
    __builtin_amdgcn_s_barrier();
    __builtin_amdgcn_sched_barrier(0);
}
DEVI void wait_vm0(){ asm volatile("s_waitcnt vmcnt(0)" ::: "memory"); }

// ---------------------------------------------------------------------------
// Kernel 1: input projection (B*L,64)@(64,256) + bias + ReLU + LN -> Y bf16
// output rows in t-major order: ri = l*512 + b. grid 1024 x 256 thr.
// ---------------------------------------------------------------------------
__global__ __launch_bounds__(256) void k_inproj(
    const float* __restrict__ X, const float* __restrict__ W,
    const float* __restrict__ bias, const float* __restrict__ g,
    const float* __restrict__ beta, uint16_t* __restrict__ Y)
{
    __shared__ __align__(16) char As[64 * 128];
    __shared__ __align__(16) char Bs[256 * 128];
    const int tid = threadIdx.x;
    const long rowbase = (long)blockIdx.x * 64;

    #pragma unroll
    for (int it = 0; it < 2; ++it) {
        int c = it * 256 + tid; int r = c >> 3, cc = c & 7;
        bf16x8 v = cvt8(X + (rowbase + r) * 64 + cc * 8);
        *(int4v*)(As + r * 128 + ((cc * 16) ^ ((r & 7) << 4))) = asint4(v);
    }
    #pragma unroll
    for (int it = 0; it < 8; ++it) {
        int c = it * 256 + tid; int r = c >> 3, cc = c & 7;
        bf16x8 v = cvt8(W + r * 64 + cc * 8);
        *(int4v*)(Bs + r * 128 + ((cc * 16) ^ ((r & 7) << 4))) = asint4(v);
    }
    __syncthreads();

    const int w = tid >> 6, l = tid & 63, lr = l & 15, lg = l >> 4;
    f32x4 acc[16];
    #pragma unroll
    for (int i = 0; i < 16; ++i) acc[i] = (f32x4){0.f, 0.f, 0.f, 0.f};
    const int arow = w * 16 + lr;
    #pragma unroll
    for (int ks = 0; ks < 2; ++ks) {
        bf16x8 a = *(bf16x8*)(As + arow * 128 + ((ks * 64 + lg * 16) ^ ((arow & 7) << 4)));
        #pragma unroll
        for (int tl = 0; tl < 16; ++tl) {
            int n = tl * 16 + lr;
            bf16x8 b = *(bf16x8*)(Bs + n * 128 + ((ks * 64 + lg * 16) ^ ((n & 7) << 4)));
            acc[tl] = mfma16(a, b, acc[tl]);
        }
    }
    float gv[16], bv[16], biasv[16];
    #pragma unroll
    for (int tl = 0; tl < 16; ++tl) {
        int col = tl * 16 + lr;
        gv[tl] = g[col]; bv[tl] = beta[col]; biasv[tl] = bias[col];
    }
    #pragma unroll
    for (int i = 0; i < 4; ++i) {
        float s = 0.f, sq = 0.f, v[16];
        #pragma unroll
        for (int tl = 0; tl < 16; ++tl) {
            float xv = acc[tl][i] + biasv[tl]; xv = fmaxf(xv, 0.f);
            v[tl] = xv; s += xv; sq += xv * xv;
        }
        #pragma unroll
        for (int d = 1; d < 16; d <<= 1) { s += __shfl_xor(s, d); sq += __shfl_xor(sq, d); }
        float mean = s * (1.f / 256.f);
        float var  = sq * (1.f / 256.f) - mean * mean;
        float sc   = rsqrtf(var + 1e-5f);
        long row = rowbase + w * 16 + lg * 4 + i;
        long ri  = ((row & 127) << 9) + (row >> 7);          // t-major
        #pragma unroll
        for (int tl = 0; tl < 16; ++tl)
            Y[ri * 256 + tl * 16 + lr] = f2bf((v[tl] - mean) * sc * gv[tl] + bv[tl]);
    }
}

// ---------------------------------------------------------------------------
// Kernel 2: input-gate GEMM, persistent-N. XG[ri,768] = A[ri,KIN]@W^T + bias.
// Block owns one 192-col strip (B staged once in LDS), loops 8 x 128-row tiles.
// A-fragments loaded directly global->reg (rows = t-major ri, contiguous KIN).
// grid (64, 4) x 512 thr (8 waves, wave = 16 rows x 192 cols).
// ---------------------------------------------------------------------------
template<int KIN, bool ZBUILD>
__global__ __launch_bounds__(512) void k_xg(
    const uint16_t* __restrict__ A, const float* __restrict__ W,
    const float* __restrict__ bias, uint16_t* __restrict__ XG,
    const float* __restrict__ zbuf, const float* __restrict__ noise)
{
    constexpr int KB = KIN * 2;           // bf16 row bytes
    constexpr int KS = KIN / 32;          // mfma k-steps
    __shared__ __align__(16) char Bs[192 * KB];
    const int tid = threadIdx.x;
    const int nb = blockIdx.y;

    constexpr int CPR = KIN / 8;          // 8-f32 chunks per row
    for (int c = tid; c < 192 * CPR; c += 512) {
        int r = c / CPR, cc = c % CPR;
        bf16x8 v = cvt8(W + (long)(nb * 192 + r) * KIN + cc * 8);
        *(int4v*)(Bs + r * KB + ((cc * 16) ^ ((r & 7) << 4))) = asint4(v);
    }
    __syncthreads();

    const int w = tid >> 6, l = tid & 63, lr = l & 15, lg = l >> 4;
    float bvs[12];
    #pragma unroll
    for (int tl = 0; tl < 12; ++tl) bvs[tl] = bias[nb * 192 + tl * 16 + lr];

    for (int rt = 0; rt < 8; ++rt) {
        const long rowb = ((long)blockIdx.x * 8 + rt) * 128;
        const long ria = rowb + w * 16 + lr;          // A row for this lane
        bf16x8 a[KS];
        if constexpr (!ZBUILD) {
            #pragma unroll
            for (int ks = 0; ks < KS; ++ks)
                a[ks] = *(const bf16x8*)(A + ria * KIN + ks * 32 + lg * 8);
        } else {
            int b = (int)(ria & 511), t = (int)(ria >> 9);
            #pragma unroll
            for (int ks = 0; ks < KS; ++ks) {
                int k0 = ks * 32 + lg * 8;
                const float* zr = zbuf + b * 64 + k0;
                const float* nr = noise + ((long)b * 128 + t) * 64 + k0;
                f32x4 z0 = *(const f32x4*)zr, z1 = *(const f32x4*)(zr + 4);
                f32x4 n0 = *(const f32x4*)nr, n1 = *(const f32x4*)(nr + 4);
                union { bf16x8 v; uint16_t u[8]; } un;
                #pragma unroll
                for (int e = 0; e < 4; ++e) {
                    un.u[e]     = f2bf(z0[e] + 0.05f * n0[e]);
                    un.u[4 + e] = f2bf(z1[e] + 0.05f * n1[e]);
                }
                a[ks] = un.v;
            }
        }
        f32x4 acc[12];
        #pragma unroll
        for (int i = 0; i < 12; ++i) acc[i] = (f32x4){0.f, 0.f, 0.f, 0.f};
        #pragma unroll
        for (int ks = 0; ks < KS; ++ks) {
            #pragma unroll
            for (int tl = 0; tl < 12; ++tl) {
                int n = tl * 16 + lr;
                bf16x8 b = *(bf16x8*)(Bs + n * KB + ((ks * 64 + lg * 16) ^ ((n & 7) << 4)));
                acc[tl] = mfma16(a[ks], b, acc[tl]);
            }
        }
        #pragma unroll
        for (int tl = 0; tl < 12; ++tl) {
            int colg = nb * 192 + tl * 16 + lr;
            #pragma unroll
            for (int i = 0; i < 4; ++i) {
                long row = rowb + w * 16 + lg * 4 + i;
                XG[row * 768 + colg] = f2bf(acc[tl][i] + bvs[tl]);
            }
        }
    }
}

// ---------------------------------------------------------------------------
// Kernel 3: persistent GRU. grid = 128 blocks x 512 thr (8 waves), 4 rows/block.
// XG is t-major: step t reads one contiguous 6 KB burst.
// Per step: 1 raw barrier (lgkm only); XG prefetch waited with dedicated vmcnt(0)
// before Y stores are issued, so stores are never drained in-loop.
// ---------------------------------------------------------------------------
__global__ __launch_bounds__(512) void k_gru(
    const uint16_t* __restrict__ XG, const float* __restrict__ Whh,
    const float* __restrict__ bhh, uint16_t* __restrict__ Y,
    float* __restrict__ hlast)
{
    constexpr int L = 128;
    constexpr int XROW = 1552;                        // 1536 B + 16 pad
    __shared__ __align__(16) char Abuf[2][16 * 512];  // h bf16 (rows 4..15 = 0)
    __shared__ __align__(16) char Wt[768 * 128];      // Whh K-tail (k 192..255)
    __shared__ __align__(16) char Xb[2][4 * XROW];    // xg double buffer
    const int tid = threadIdx.x;
    const int w = tid >> 6, l = tid & 63, lr = l & 15, lg = l >> 4;
    const int rowg0 = blockIdx.x * 4;

    for (int i = tid; i < 2 * 16 * 512 / 4; i += 512) ((uint32_t*)Abuf)[i] = 0;

    #pragma unroll
    for (int it = 0; it < 12; ++it) {                 // stage Whh K-tail
        int c = it * 512 + tid; int r = c >> 3, cc = c & 7;
        bf16x8 v = cvt8(Whh + (long)r * 256 + 192 + cc * 8);
        *(int4v*)(Wt + r * 128 + ((cc * 16) ^ ((r & 7) << 4))) = asint4(v);
    }

    int gb[6];
    #pragma unroll
    for (int tl = 0; tl < 6; ++tl) gb[tl] = (tl >> 1) * 256 + w * 32 + (tl & 1) * 16;
    bf16x8 wf[6][6];
    #pragma unroll
    for (int tl = 0; tl < 6; ++tl) {
        int n = gb[tl] + lr;
        #pragma unroll
        for (int ks = 0; ks < 6; ++ks)
            wf[tl][ks] = cvt8(Whh + (long)n * 256 + ks * 32 + lg * 8);
    }
    float bh[6];
    #pragma unroll
    for (int tl = 0; tl < 6; ++tl) bh[tl] = bhh[gb[tl] + lr];

    const int xr_ = tid / 96, xc_ = tid % 96;         // staging coords (tid<384)
    if (tid < 384)
        *(int4v*)(Xb[0] + xr_ * XROW + xc_ * 16) =
            *(const int4v*)(XG + ((long)rowg0 + xr_) * 768 + xc_ * 8);

    float hreg[2][4] = {{0.f,0.f,0.f,0.f},{0.f,0.f,0.f,0.f}};
    const bool wy = (Y != nullptr);
    __syncthreads();

    for (int t = 0; t < L; ++t) {
        const int p = t & 1;
        int4v gx;
        const bool havegx = (t + 1 < L) && (tid < 384);
        if (havegx)
            gx = *(const int4v*)(XG + ((long)(t + 1) * 512 + rowg0 + xr_) * 768 + xc_ * 8);

        f32x4 acc[6];
        #pragma unroll
        for (int i = 0; i < 6; ++i) acc[i] = (f32x4){0.f, 0.f, 0.f, 0.f};
        #pragma unroll
        for (int ks = 0; ks < 8; ++ks) {
            bf16x8 a = *(bf16x8*)(Abuf[p] + lr * 512 + ((ks * 64 + lg * 16) ^ ((lr & 7) << 4)));
            if (ks < 6) {
                #pragma unroll
                for (int tl = 0; tl < 6; ++tl) acc[tl] = mfma16(a, wf[tl][ks], acc[tl]);
            } else {
                #pragma unroll
                for (int tl = 0; tl < 6; ++tl) {
                    int n = gb[tl] + lr;
                    bf16x8 b = *(bf16x8*)(Wt + n * 128 + (((ks - 6) * 64 + lg * 16) ^ ((n & 7) << 4)));
                    acc[tl] = mfma16(a, b, acc[tl]);
                }
            }
        }

        uint16_t hbv[2][4];
        if (lg == 0) {                                // rows 0..3 live on lg==0
            const char* xb = Xb[p];
            #pragma unroll
            for (int sub = 0; sub < 2; ++sub) {
                #pragma unroll
                for (int i = 0; i < 4; ++i) {
                    int colr = w * 32 + sub * 16 + lr;
                    float xr = bf2f(*(const uint16_t*)(xb + i * XROW + (colr)       * 2));
                    float xz = bf2f(*(const uint16_t*)(xb + i * XROW + (256 + colr) * 2));
                    float xn = bf2f(*(const uint16_t*)(xb + i * XROW + (512 + colr) * 2));
                    float rg_ = sigm(xr + acc[0 + sub][i] + bh[0 + sub]);
                    float zg  = sigm(xz + acc[2 + sub][i] + bh[2 + sub]);
                    float nn  = tanhfast(xn + rg_ * (acc[4 + sub][i] + bh[4 + sub]));
                    float h = nn + zg * (hreg[sub][i] - nn);
                    hreg[sub][i] = h;
                    uint16_t hb = f2bf(h);
                    hbv[sub][i] = hb;
                    *(uint16_t*)(Abuf[p ^ 1] + i * 512 +
                        (((colr * 2) & ~15) ^ ((i & 7) << 4)) + ((colr * 2) & 15)) = hb;
                }
            }
        }

        wait_vm0();                                   // only the XG prefetch is in flight
        if (havegx) *(int4v*)(Xb[p ^ 1] + xr_ * XROW + xc_ * 16) = gx;
        if (wy && lg == 0) {
            #pragma unroll
            for (int sub = 0; sub < 2; ++sub)
                #pragma unroll
                for (int i = 0; i < 4; ++i)
                    Y[((long)t * 512 + rowg0 + i) * 256 + w * 32 + sub * 16 + lr] = hbv[sub][i];
        }
        bar_lds();
    }
    if (hlast != nullptr && lg == 0) {
        #pragma unroll
        for (int sub = 0; sub < 2; ++sub)
            #pragma unroll
            for (int i = 0; i < 4; ++i)
                hlast[((long)rowg0 + i) * 256 + w * 32 + sub * 16 + lr] = hreg[sub][i];
    }
}

// ---------------------------------------------------------------------------
// Kernel 4: mu / log_var / z.  grid = 256 blocks x 256 thr, 2 rows/block.
// ---------------------------------------------------------------------------
__global__ __launch_bounds__(256) void k_z(
    const float* __restrict__ hlast, const float* __restrict__ muW,
    const float* __restrict__ mub, const float* __restrict__ lvW,
    const float* __restrict__ lvb, const float* __restrict__ eps,
    float* __restrict__ mu_out, float* __restrict__ lv_out,
    float* __restrict__ zout)
{
    __shared__ float hrow[2][256];
    __shared__ float res[2][128];
    const int tid = threadIdx.x;
    const long row0 = (long)blockIdx.x * 2;
    for (int i = tid; i < 512; i += 256) ((float*)hrow)[i] = hlast[row0 * 256 + i];
    __syncthreads();
    const int lrr = tid >> 7, c = tid & 127;
    const float* Wr = (c < 64 ? muW : lvW) + (long)(c & 63) * 256;
    float acc = (c < 64) ? mub[c] : lvb[c & 63];
    const float* hr = hrow[lrr];
    #pragma unroll 8
    for (int k = 0; k < 256; k += 4) {
        f32x4 wv = *(const f32x4*)(Wr + k);
        #pragma unroll
        for (int e = 0; e < 4; ++e) acc += hr[k + e] * wv[e];
    }
    res[lrr][c] = acc;
    long row = row0 + lrr;
    if (c < 64) mu_out[row * 64 + c] = acc;
    else        lv_out[row * 64 + (c & 63)] = acc;
    __syncthreads();
    if (c < 64) {
        float m = res[lrr][c], lv = res[lrr][64 + c];
        zout[row * 64 + c] = m + eps[row * 64 + c] * __expf(0.5f * lv);
    }
}

// ---------------------------------------------------------------------------
// Kernel 5: post proj + ReLU + LN, then output proj + tanh -> x_hat (f32).
// D1 rows are t-major ri; x_hat written b-major. grid 1024 x 256 thr.
// ---------------------------------------------------------------------------
__global__ __launch_bounds__(256) void k_post(
    const uint16_t* __restrict__ D1, const float* __restrict__ pW,
    const float* __restrict__ pb, const float* __restrict__ pg,
    const float* __restrict__ pbeta, const float* __restrict__ oW,
    const float* __restrict__ ob, float* __restrict__ xhat)
{
    __shared__ __align__(16) char Bs[256 * 512];
    const int tid = threadIdx.x;
    const long rowbase = (long)blockIdx.x * 64;
    #pragma unroll
    for (int it = 0; it < 32; ++it) {
        int c = it * 256 + tid; int r = c >> 5, cc = c & 31;
        bf16x8 v = cvt8(pW + r * 256 + cc * 8);
        *(int4v*)(Bs + r * 512 + ((cc * 16) ^ ((r & 7) << 4))) = asint4(v);
    }
    __syncthreads();
    const int w = tid >> 6, l = tid & 63, lr = l & 15, lg = l >> 4;
    const long arow = rowbase + w * 16 + lr;
    bf16x8 af[8];
    #pragma unroll
    for (int ks = 0; ks < 8; ++ks) af[ks] = *(const bf16x8*)(D1 + arow * 256 + ks * 32 + lg * 8);
    f32x4 acc[16];
    #pragma unroll
    for (int i = 0; i < 16; ++i) acc[i] = (f32x4){0.f, 0.f, 0.f, 0.f};
    #pragma unroll
    for (int ks = 0; ks < 8; ++ks) {
        #pragma unroll
        for (int tl = 0; tl < 16; ++tl) {
            int n = tl * 16 + lr;
            bf16x8 b = *(bf16x8*)(Bs + n * 512 + ((ks * 64 + lg * 16) ^ ((n & 7) << 4)));
            acc[tl] = mfma16(af[ks], b, acc[tl]);
        }
    }
    float gv[16], bv[16], biasv[16];
    #pragma unroll
    for (int tl = 0; tl < 16; ++tl) {
        int col = tl * 16 + lr;
        gv[tl] = pg[col]; bv[tl] = pbeta[col]; biasv[tl] = pb[col];
    }
    uint16_t dl[16][4];
    #pragma unroll
    for (int i = 0; i < 4; ++i) {
        float s = 0.f, sq = 0.f, v[16];
        #pragma unroll
        for (int tl = 0; tl < 16; ++tl) {
            float xv = acc[tl][i] + biasv[tl]; xv = fmaxf(xv, 0.f);
            v[tl] = xv; s += xv; sq += xv * xv;
        }
        #pragma unroll
        for (int d = 1; d < 16; d <<= 1) { s += __shfl_xor(s, d); sq += __shfl_xor(sq, d); }
        float mean = s * (1.f / 256.f);
        float var  = sq * (1.f / 256.f) - mean * mean;
        float sc   = rsqrtf(var + 1e-5f);
        #pragma unroll
        for (int tl = 0; tl < 16; ++tl)
            dl[tl][i] = f2bf((v[tl] - mean) * sc * gv[tl] + bv[tl]);
    }
    __syncthreads();
    #pragma unroll
    for (int tl = 0; tl < 16; ++tl) {
        int col = tl * 16 + lr;
        #pragma unroll
        for (int i = 0; i < 4; ++i) {
            int row = w * 16 + lg * 4 + i;
            *(uint16_t*)(Bs + row * 512 + (((col * 2) & ~15) ^ ((row & 7) << 4)) + ((col * 2) & 15)) = dl[tl][i];
        }
    }
    __syncthreads();
    const int ar2 = w * 16 + lr;
    f32x4 acc2[4];
    #pragma unroll
    for (int i = 0; i < 4; ++i) acc2[i] = (f32x4){0.f, 0.f, 0.f, 0.f};
    #pragma unroll
    for (int ks = 0; ks < 8; ++ks) {
        bf16x8 a = *(bf16x8*)(Bs + ar2 * 512 + ((ks * 64 + lg * 16) ^ ((ar2 & 7) << 4)));
        #pragma unroll
        for (int tl = 0; tl < 4; ++tl) {
            int n = tl * 16 + lr;
            bf16x8 b = cvt8(oW + n * 256 + ks * 32 + lg * 8);
            acc2[tl] = mfma16(a, b, acc2[tl]);
        }
    }
    #pragma unroll
    for (int tl = 0; tl < 4; ++tl) {
        int col = tl * 16 + lr;
        float bo = ob[col];
        #pragma unroll
        for (int i = 0; i < 4; ++i) {
            long ri = rowbase + w * 16 + lg * 4 + i;
            long b = ri & 511, t = ri >> 9;
            xhat[(b * 128 + t) * 64 + col] = tanhfast(acc2[tl][i] + bo);
        }
    }
}

// ---------------------------------------------------------------------------
extern "C" void kernel_launch(void* const* d_in, const int* in_sizes, int n_in,
                              void* d_out, int out_size, void* d_ws, size_t ws_size,
                              hipStream_t stream)
{
    (void)in_sizes; (void)n_in; (void)out_size; (void)ws_size;
    const float* x     = (const float*)d_in[0];
    const float* eps   = (const float*)d_in[1];
    const float* dnz   = (const float*)d_in[2];
    const float* in_W  = (const float*)d_in[3];
    const float* in_b  = (const float*)d_in[4];
    const float* in_g  = (const float*)d_in[5];
    const float* in_be = (const float*)d_in[6];
    const float* eW0i  = (const float*)d_in[7];
    const float* eW0h  = (const float*)d_in[8];
    const float* eb0i  = (const float*)d_in[9];
    const float* eb0h  = (const float*)d_in[10];
    const float* eW1i  = (const float*)d_in[11];
    const float* eW1h  = (const float*)d_in[12];
    const float* eb1i  = (const float*)d_in[13];
    const float* eb1h  = (const float*)d_in[14];
    const float* mu_W  = (const float*)d_in[15];
    const float* mu_b  = (const float*)d_in[16];
    const float* lv_W  = (const float*)d_in[17];
    const float* lv_b  = (const float*)d_in[18];
    const float* dW0i  = (const float*)d_in[19];
    const float* dW0h  = (const float*)d_in[20];
    const float* db0i  = (const float*)d_in[21];
    const float* db0h  = (const float*)d_in[22];
    const float* dW1i  = (const float*)d_in[23];
    const float* dW1h  = (const float*)d_in[24];
    const float* db1i  = (const float*)d_in[25];
    const float* db1h  = (const float*)d_in[26];
    const float* postW = (const float*)d_in[27];
    const float* postb = (const float*)d_in[28];
    const float* postg = (const float*)d_in[29];
    const float* postbe= (const float*)d_in[30];
    const float* outW  = (const float*)d_in[31];
    const float* outb  = (const float*)d_in[32];

    char* ws = (char*)d_ws;
    uint16_t* XG   = (uint16_t*)(ws);                 // 65536*768*2 = 100663296 B
    uint16_t* YA   = (uint16_t*)(ws + 100663296);     // 33554432 B
    uint16_t* YB   = (uint16_t*)(ws + 134217728);     // 33554432 B
    float*    hlast= (float*)   (ws + 167772160);     // 524288 B
    float*    zbuf = (float*)   (ws + 168296448);     // 131072 B

    float* out    = (float*)d_out;
    float* mu_out = out + 4194304;
    float* lv_out = out + 4194304 + 32768;

    dim3 b256(256), b512(512);
    dim3 gxg(64, 4);

    k_inproj<<<1024, b256, 0, stream>>>(x, in_W, in_b, in_g, in_be, YA);
    k_xg<256,false><<<gxg, b512, 0, stream>>>(YA, eW0i, eb0i, XG, nullptr, nullptr);
    k_gru<<<128, b512, 0, stream>>>(XG, eW0h, eb0h, YB, nullptr);
    k_xg<256,false><<<gxg, b512, 0, stream>>>(YB, eW1i, eb1i, XG, nullptr, nullptr);
    k_gru<<<128, b512, 0, stream>>>(XG, eW1h, eb1h, nullptr, hlast);
    k_z<<<256, b256, 0, stream>>>(hlast, mu_W, mu_b, lv_W, lv_b, eps, mu_out, lv_out, zbuf);
    k_xg<64,true><<<gxg, b512, 0, stream>>>(nullptr, dW0i, db0i, XG, zbuf, dnz);
    k_gru<<<128, b512, 0, stream>>>(XG, dW0h, db0h, YA, nullptr);
    k_xg<256,false><<<gxg, b512, 0, stream>>>(YA, dW1i, db1i, XG, nullptr, nullptr);
    k_gru<<<128, b512, 0, stream>>>(XG, dW1h, db1h, YB, nullptr);
    k_post<<<1024, b256, 0, stream>>>(YB, postW, postb, postg, postbe, outW, outb, out);
}

// Round 4
// 1494.573 us; speedup vs baseline: 1.3451x; 1.2948x over previous
//
#include <hip/hip_runtime.h>
#include <hip/hip_bf16.h>
#include <stdint.h>

#define DEVI static __device__ __forceinline__

typedef __bf16 bf16x8 __attribute__((ext_vector_type(8)));
typedef float f32x4 __attribute__((ext_vector_type(4)));
typedef int   int4v __attribute__((ext_vector_type(4)));

DEVI float bf2f(uint16_t u){ uint32_t x = ((uint32_t)u) << 16; float f; __builtin_memcpy(&f, &x, 4); return f; }
DEVI uint16_t f2bf(float f){ uint32_t u; __builtin_memcpy(&u, &f, 4); uint32_t r = (u + 0x7FFFu + ((u >> 16) & 1u)) >> 16; return (uint16_t)r; }
DEVI float frcp(float x){ return __builtin_amdgcn_rcpf(x); }
DEVI float sigm(float x){ return frcp(1.f + __expf(-x)); }
DEVI float tanhfast(float x){ return 1.f - 2.f * frcp(1.f + __expf(2.f * x)); }
DEVI f32x4 mfma16(bf16x8 a, bf16x8 b, f32x4 c){ return __builtin_amdgcn_mfma_f32_16x16x32_bf16(a, b, c, 0, 0, 0); }

DEVI bf16x8 cvt8(const float* __restrict__ p){
    f32x4 a = *(const f32x4*)p, b = *(const f32x4*)(p + 4);
    union { bf16x8 v; uint16_t u[8]; } r;
    #pragma unroll
    for (int e = 0; e < 4; ++e) { r.u[e] = f2bf(a[e]); r.u[4 + e] = f2bf(b[e]); }
    return r.v;
}
DEVI int4v asint4(bf16x8 v){ int4v r; __builtin_memcpy(&r, &v, 16); return r; }

// raw barrier: lgkm drain only (vm ops — prefetch loads / Y stores — stay in flight)
DEVI void bar_lds(){
    asm volatile("s_waitcnt lgkmcnt(0)" ::: "memory");
    __builtin_amdgcn_s_barrier();
    __builtin_amdgcn_sched_barrier(0);
}

// ---------------------------------------------------------------------------
// Kernel 1: input projection (B*L,64)@(64,256) + bias + ReLU + LN -> Y bf16
// output rows in t-major order: ri = l*512 + b. grid 1024 x 256 thr.
// ---------------------------------------------------------------------------
__global__ __launch_bounds__(256) void k_inproj(
    const float* __restrict__ X, const float* __restrict__ W,
    const float* __restrict__ bias, const float* __restrict__ g,
    const float* __restrict__ beta, uint16_t* __restrict__ Y)
{
    __shared__ __align__(16) char As[64 * 128];
    __shared__ __align__(16) char Bs[256 * 128];
    const int tid = threadIdx.x;
    const long rowbase = (long)blockIdx.x * 64;

    #pragma unroll
    for (int it = 0; it < 2; ++it) {
        int c = it * 256 + tid; int r = c >> 3, cc = c & 7;
        bf16x8 v = cvt8(X + (rowbase + r) * 64 + cc * 8);
        *(int4v*)(As + r * 128 + ((cc * 16) ^ ((r & 7) << 4))) = asint4(v);
    }
    #pragma unroll
    for (int it = 0; it < 8; ++it) {
        int c = it * 256 + tid; int r = c >> 3, cc = c & 7;
        bf16x8 v = cvt8(W + r * 64 + cc * 8);
        *(int4v*)(Bs + r * 128 + ((cc * 16) ^ ((r & 7) << 4))) = asint4(v);
    }
    __syncthreads();

    const int w = tid >> 6, l = tid & 63, lr = l & 15, lg = l >> 4;
    f32x4 acc[16];
    #pragma unroll
    for (int i = 0; i < 16; ++i) acc[i] = (f32x4){0.f, 0.f, 0.f, 0.f};
    const int arow = w * 16 + lr;
    #pragma unroll
    for (int ks = 0; ks < 2; ++ks) {
        bf16x8 a = *(bf16x8*)(As + arow * 128 + ((ks * 64 + lg * 16) ^ ((arow & 7) << 4)));
        #pragma unroll
        for (int tl = 0; tl < 16; ++tl) {
            int n = tl * 16 + lr;
            bf16x8 b = *(bf16x8*)(Bs + n * 128 + ((ks * 64 + lg * 16) ^ ((n & 7) << 4)));
            acc[tl] = mfma16(a, b, acc[tl]);
        }
    }
    float gv[16], bv[16], biasv[16];
    #pragma unroll
    for (int tl = 0; tl < 16; ++tl) {
        int col = tl * 16 + lr;
        gv[tl] = g[col]; bv[tl] = beta[col]; biasv[tl] = bias[col];
    }
    #pragma unroll
    for (int i = 0; i < 4; ++i) {
        float s = 0.f, sq = 0.f, v[16];
        #pragma unroll
        for (int tl = 0; tl < 16; ++tl) {
            float xv = acc[tl][i] + biasv[tl]; xv = fmaxf(xv, 0.f);
            v[tl] = xv; s += xv; sq += xv * xv;
        }
        #pragma unroll
        for (int d = 1; d < 16; d <<= 1) { s += __shfl_xor(s, d); sq += __shfl_xor(sq, d); }
        float mean = s * (1.f / 256.f);
        float var  = sq * (1.f / 256.f) - mean * mean;
        float sc   = rsqrtf(var + 1e-5f);
        long row = rowbase + w * 16 + lg * 4 + i;
        long ri  = ((row & 127) << 9) + (row >> 7);          // t-major
        #pragma unroll
        for (int tl = 0; tl < 16; ++tl)
            Y[ri * 256 + tl * 16 + lr] = f2bf((v[tl] - mean) * sc * gv[tl] + bv[tl]);
    }
}

// ---------------------------------------------------------------------------
// Kernel 2: input-gate GEMM, persistent-N. XG[ri,768] = A[ri,KIN]@W^T + bias.
// Block owns one 192-col strip (B staged once in LDS), loops 8 x 128-row tiles.
// grid (64, 4) x 512 thr (8 waves, wave = 16 rows x 192 cols).
// ---------------------------------------------------------------------------
template<int KIN, bool ZBUILD>
__global__ __launch_bounds__(512) void k_xg(
    const uint16_t* __restrict__ A, const float* __restrict__ W,
    const float* __restrict__ bias, uint16_t* __restrict__ XG,
    const float* __restrict__ zbuf, const float* __restrict__ noise)
{
    constexpr int KB = KIN * 2;           // bf16 row bytes
    constexpr int KS = KIN / 32;          // mfma k-steps
    __shared__ __align__(16) char Bs[192 * KB];
    const int tid = threadIdx.x;
    const int nb = blockIdx.y;

    constexpr int CPR = KIN / 8;          // 8-f32 chunks per row
    for (int c = tid; c < 192 * CPR; c += 512) {
        int r = c / CPR, cc = c % CPR;
        bf16x8 v = cvt8(W + (long)(nb * 192 + r) * KIN + cc * 8);
        *(int4v*)(Bs + r * KB + ((cc * 16) ^ ((r & 7) << 4))) = asint4(v);
    }
    __syncthreads();

    const int w = tid >> 6, l = tid & 63, lr = l & 15, lg = l >> 4;
    float bvs[12];
    #pragma unroll
    for (int tl = 0; tl < 12; ++tl) bvs[tl] = bias[nb * 192 + tl * 16 + lr];

    for (int rt = 0; rt < 8; ++rt) {
        const long rowb = ((long)blockIdx.x * 8 + rt) * 128;
        const long ria = rowb + w * 16 + lr;          // A row for this lane
        bf16x8 a[KS];
        if constexpr (!ZBUILD) {
            #pragma unroll
            for (int ks = 0; ks < KS; ++ks)
                a[ks] = *(const bf16x8*)(A + ria * KIN + ks * 32 + lg * 8);
        } else {
            int b = (int)(ria & 511), t = (int)(ria >> 9);
            #pragma unroll
            for (int ks = 0; ks < KS; ++ks) {
                int k0 = ks * 32 + lg * 8;
                const float* zr = zbuf + b * 64 + k0;
                const float* nr = noise + ((long)b * 128 + t) * 64 + k0;
                f32x4 z0 = *(const f32x4*)zr, z1 = *(const f32x4*)(zr + 4);
                f32x4 n0 = *(const f32x4*)nr, n1 = *(const f32x4*)(nr + 4);
                union { bf16x8 v; uint16_t u[8]; } un;
                #pragma unroll
                for (int e = 0; e < 4; ++e) {
                    un.u[e]     = f2bf(z0[e] + 0.05f * n0[e]);
                    un.u[4 + e] = f2bf(z1[e] + 0.05f * n1[e]);
                }
                a[ks] = un.v;
            }
        }
        f32x4 acc[12];
        #pragma unroll
        for (int i = 0; i < 12; ++i) acc[i] = (f32x4){0.f, 0.f, 0.f, 0.f};
        #pragma unroll
        for (int ks = 0; ks < KS; ++ks) {
            #pragma unroll
            for (int tl = 0; tl < 12; ++tl) {
                int n = tl * 16 + lr;
                bf16x8 b = *(bf16x8*)(Bs + n * KB + ((ks * 64 + lg * 16) ^ ((n & 7) << 4)));
                acc[tl] = mfma16(a[ks], b, acc[tl]);
            }
        }
        #pragma unroll
        for (int tl = 0; tl < 12; ++tl) {
            int colg = nb * 192 + tl * 16 + lr;
            #pragma unroll
            for (int i = 0; i < 4; ++i) {
                long row = rowb + w * 16 + lg * 4 + i;
                XG[row * 768 + colg] = f2bf(acc[tl][i] + bvs[tl]);
            }
        }
    }
}

// ---------------------------------------------------------------------------
// Kernel 3: persistent GRU. grid = 256 blocks x 512 thr (8 waves), 2 rows/block.
// Whh k[0,224) in VGPRs (42 frags), k[224,256) in LDS (80B-stride, conflict-free).
// h stored as 2 rows x 512B in LDS; MFMA A-read maps row=lr&1 (broadcast) so
// the M=16 padding costs no memory traffic. Every lane owns one (row,col)
// h-element: gates all-lane, 1 ds_write + 1 Y store + 3 xg prefetch loads.
// One lgkm-only barrier per step; vm ops ride across it.
// ---------------------------------------------------------------------------
__global__ __launch_bounds__(512, 2) void k_gru(
    const uint16_t* __restrict__ XG, const float* __restrict__ Whh,
    const float* __restrict__ bhh, uint16_t* __restrict__ Y,
    float* __restrict__ hlast)
{
    constexpr int L = 128;
    __shared__ __align__(16) char Abuf[2][2 * 512];   // h bf16, 2 rows, swizzled
    __shared__ __align__(16) char Wt[768 * 80];        // Whh k-tail [224,256)
    const int tid = threadIdx.x;
    const int w = tid >> 6, l = tid & 63, lr = l & 15, lg = l >> 4;
    const int rowg0 = blockIdx.x * 2;

    ((uint32_t*)Abuf)[tid] = 0;                        // zero both h buffers

    #pragma unroll
    for (int it = 0; it < 6; ++it) {                   // stage Wt: 768 x 4 chunks
        int c = it * 512 + tid; int r = c >> 2, cc = c & 3;
        bf16x8 v = cvt8(Whh + (long)r * 256 + 224 + cc * 8);
        *(int4v*)(Wt + r * 80 + cc * 16) = asint4(v);
    }

    int gb[6];
    #pragma unroll
    for (int tl = 0; tl < 6; ++tl) gb[tl] = (tl >> 1) * 256 + w * 32 + (tl & 1) * 16;
    bf16x8 wf[6][7];
    #pragma unroll
    for (int tl = 0; tl < 6; ++tl)
        #pragma unroll
        for (int ks = 0; ks < 7; ++ks)
            wf[tl][ks] = cvt8(Whh + (long)(gb[tl] + lr) * 256 + ks * 32 + lg * 8);

    const int i_  = lg & 1;                            // local batch row 0/1
    const int sub = (lg >> 1) & 1;
    const int col = w * 32 + sub * 16 + lr;            // h column 0..255
    const float bR = bhh[col], bZ = bhh[256 + col], bN = bhh[512 + col];
    const long rowl = rowg0 + i_;                      // global batch row
    const int wrbyte = i_ * 512 + (((col * 2) & ~15) ^ (i_ << 4)) + ((col * 2) & 15);

    uint16_t xga0 = XG[rowl * 768 + col];              // xg(t=0) prefetch
    uint16_t xga1 = XG[rowl * 768 + 256 + col];
    uint16_t xga2 = XG[rowl * 768 + 512 + col];
    float h = 0.f;
    const bool wy = (Y != nullptr);
    __syncthreads();

    for (int t = 0; t < L; ++t) {
        const int p = t & 1;
        f32x4 acc[6];
        #pragma unroll
        for (int i = 0; i < 6; ++i) acc[i] = (f32x4){0.f, 0.f, 0.f, 0.f};
        #pragma unroll
        for (int ks = 0; ks < 8; ++ks) {
            bf16x8 a = *(bf16x8*)(Abuf[p] + (lr & 1) * 512 + ((ks * 64 + lg * 16) ^ ((lr & 1) << 4)));
            if (ks < 7) {
                #pragma unroll
                for (int tl = 0; tl < 6; ++tl) acc[tl] = mfma16(a, wf[tl][ks], acc[tl]);
            } else {
                #pragma unroll
                for (int tl = 0; tl < 6; ++tl) {
                    bf16x8 b = *(bf16x8*)(Wt + (gb[tl] + lr) * 80 + lg * 16);
                    acc[tl] = mfma16(a, b, acc[tl]);
                }
            }
        }
        // gate pre-activations: select this lane's (row,col) from replicated acc
        float pre0, pre1, pre2;
        {
            float a0 = i_ ? acc[0][1] : acc[0][0];
            float a1 = i_ ? acc[1][1] : acc[1][0];
            pre0 = sub ? a1 : a0;
            float b0 = i_ ? acc[2][1] : acc[2][0];
            float b1 = i_ ? acc[3][1] : acc[3][0];
            pre1 = sub ? b1 : b0;
            float c0 = i_ ? acc[4][1] : acc[4][0];
            float c1 = i_ ? acc[5][1] : acc[5][0];
            pre2 = sub ? c1 : c0;
        }
        float xr = bf2f(xga0), xz = bf2f(xga1), xn = bf2f(xga2);
        float R = sigm(xr + pre0 + bR);
        float Z = sigm(xz + pre1 + bZ);
        float N = tanhfast(xn + R * (pre2 + bN));
        h = N + Z * (h - N);
        uint16_t hb = f2bf(h);
        *(uint16_t*)(Abuf[p ^ 1] + wrbyte) = hb;

        if (t + 1 < L) {                               // prefetch xg(t+1)
            const uint16_t* src = XG + ((long)(t + 1) * 512 + rowl) * 768;
            xga0 = src[col]; xga1 = src[256 + col]; xga2 = src[512 + col];
        }
        if (wy) Y[((long)t * 512 + rowl) * 256 + col] = hb;
        bar_lds();
    }
    if (hlast) hlast[rowl * 256 + col] = h;
}

// ---------------------------------------------------------------------------
// Kernel 4: mu / log_var / z.  grid = 256 blocks x 256 thr, 2 rows/block.
// ---------------------------------------------------------------------------
__global__ __launch_bounds__(256) void k_z(
    const float* __restrict__ hlast, const float* __restrict__ muW,
    const float* __restrict__ mub, const float* __restrict__ lvW,
    const float* __restrict__ lvb, const float* __restrict__ eps,
    float* __restrict__ mu_out, float* __restrict__ lv_out,
    float* __restrict__ zout)
{
    __shared__ float hrow[2][256];
    __shared__ float res[2][128];
    const int tid = threadIdx.x;
    const long row0 = (long)blockIdx.x * 2;
    for (int i = tid; i < 512; i += 256) ((float*)hrow)[i] = hlast[row0 * 256 + i];
    __syncthreads();
    const int lrr = tid >> 7, c = tid & 127;
    const float* Wr = (c < 64 ? muW : lvW) + (long)(c & 63) * 256;
    float acc = (c < 64) ? mub[c] : lvb[c & 63];
    const float* hr = hrow[lrr];
    #pragma unroll 8
    for (int k = 0; k < 256; k += 4) {
        f32x4 wv = *(const f32x4*)(Wr + k);
        #pragma unroll
        for (int e = 0; e < 4; ++e) acc += hr[k + e] * wv[e];
    }
    res[lrr][c] = acc;
    long row = row0 + lrr;
    if (c < 64) mu_out[row * 64 + c] = acc;
    else        lv_out[row * 64 + (c & 63)] = acc;
    __syncthreads();
    if (c < 64) {
        float m = res[lrr][c], lv = res[lrr][64 + c];
        zout[row * 64 + c] = m + eps[row * 64 + c] * __expf(0.5f * lv);
    }
}

// ---------------------------------------------------------------------------
// Kernel 5: post proj + ReLU + LN, then output proj + tanh -> x_hat (f32).
// D1 rows are t-major ri; x_hat written b-major. grid 1024 x 256 thr.
// ---------------------------------------------------------------------------
__global__ __launch_bounds__(256) void k_post(
    const uint16_t* __restrict__ D1, const float* __restrict__ pW,
    const float* __restrict__ pb, const float* __restrict__ pg,
    const float* __restrict__ pbeta, const float* __restrict__ oW,
    const float* __restrict__ ob, float* __restrict__ xhat)
{
    __shared__ __align__(16) char Bs[256 * 512];
    const int tid = threadIdx.x;
    const long rowbase = (long)blockIdx.x * 64;
    #pragma unroll
    for (int it = 0; it < 32; ++it) {
        int c = it * 256 + tid; int r = c >> 5, cc = c & 31;
        bf16x8 v = cvt8(pW + r * 256 + cc * 8);
        *(int4v*)(Bs + r * 512 + ((cc * 16) ^ ((r & 7) << 4))) = asint4(v);
    }
    __syncthreads();
    const int w = tid >> 6, l = tid & 63, lr = l & 15, lg = l >> 4;
    const long arow = rowbase + w * 16 + lr;
    bf16x8 af[8];
    #pragma unroll
    for (int ks = 0; ks < 8; ++ks) af[ks] = *(const bf16x8*)(D1 + arow * 256 + ks * 32 + lg * 8);
    f32x4 acc[16];
    #pragma unroll
    for (int i = 0; i < 16; ++i) acc[i] = (f32x4){0.f, 0.f, 0.f, 0.f};
    #pragma unroll
    for (int ks = 0; ks < 8; ++ks) {
        #pragma unroll
        for (int tl = 0; tl < 16; ++tl) {
            int n = tl * 16 + lr;
            bf16x8 b = *(bf16x8*)(Bs + n * 512 + ((ks * 64 + lg * 16) ^ ((n & 7) << 4)));
            acc[tl] = mfma16(af[ks], b, acc[tl]);
        }
    }
    float gv[16], bv[16], biasv[16];
    #pragma unroll
    for (int tl = 0; tl < 16; ++tl) {
        int col = tl * 16 + lr;
        gv[tl] = pg[col]; bv[tl] = pbeta[col]; biasv[tl] = pb[col];
    }
    uint16_t dl[16][4];
    #pragma unroll
    for (int i = 0; i < 4; ++i) {
        float s = 0.f, sq = 0.f, v[16];
        #pragma unroll
        for (int tl = 0; tl < 16; ++tl) {
            float xv = acc[tl][i] + biasv[tl]; xv = fmaxf(xv, 0.f);
            v[tl] = xv; s += xv; sq += xv * xv;
        }
        #pragma unroll
        for (int d = 1; d < 16; d <<= 1) { s += __shfl_xor(s, d); sq += __shfl_xor(sq, d); }
        float mean = s * (1.f / 256.f);
        float var  = sq * (1.f / 256.f) - mean * mean;
        float sc   = rsqrtf(var + 1e-5f);
        #pragma unroll
        for (int tl = 0; tl < 16; ++tl)
            dl[tl][i] = f2bf((v[tl] - mean) * sc * gv[tl] + bv[tl]);
    }
    __syncthreads();
    #pragma unroll
    for (int tl = 0; tl < 16; ++tl) {
        int col = tl * 16 + lr;
        #pragma unroll
        for (int i = 0; i < 4; ++i) {
            int row = w * 16 + lg * 4 + i;
            *(uint16_t*)(Bs + row * 512 + (((col * 2) & ~15) ^ ((row & 7) << 4)) + ((col * 2) & 15)) = dl[tl][i];
        }
    }
    __syncthreads();
    const int ar2 = w * 16 + lr;
    f32x4 acc2[4];
    #pragma unroll
    for (int i = 0; i < 4; ++i) acc2[i] = (f32x4){0.f, 0.f, 0.f, 0.f};
    #pragma unroll
    for (int ks = 0; ks < 8; ++ks) {
        bf16x8 a = *(bf16x8*)(Bs + ar2 * 512 + ((ks * 64 + lg * 16) ^ ((ar2 & 7) << 4)));
        #pragma unroll
        for (int tl = 0; tl < 4; ++tl) {
            int n = tl * 16 + lr;
            bf16x8 b = cvt8(oW + n * 256 + ks * 32 + lg * 8);
            acc2[tl] = mfma16(a, b, acc2[tl]);
        }
    }
    #pragma unroll
    for (int tl = 0; tl < 4; ++tl) {
        int col = tl * 16 + lr;
        float bo = ob[col];
        #pragma unroll
        for (int i = 0; i < 4; ++i) {
            long ri = rowbase + w * 16 + lg * 4 + i;
            long b = ri & 511, t = ri >> 9;
            xhat[(b * 128 + t) * 64 + col] = tanhfast(acc2[tl][i] + bo);
        }
    }
}

// ---------------------------------------------------------------------------
extern "C" void kernel_launch(void* const* d_in, const int* in_sizes, int n_in,
                              void* d_out, int out_size, void* d_ws, size_t ws_size,
                              hipStream_t stream)
{
    (void)in_sizes; (void)n_in; (void)out_size; (void)ws_size;
    const float* x     = (const float*)d_in[0];
    const float* eps   = (const float*)d_in[1];
    const float* dnz   = (const float*)d_in[2];
    const float* in_W  = (const float*)d_in[3];
    const float* in_b  = (const float*)d_in[4];
    const float* in_g  = (const float*)d_in[5];
    const float* in_be = (const float*)d_in[6];
    const float* eW0i  = (const float*)d_in[7];
    const float* eW0h  = (const float*)d_in[8];
    const float* eb0i  = (const float*)d_in[9];
    const float* eb0h  = (const float*)d_in[10];
    const float* eW1i  = (const float*)d_in[11];
    const float* eW1h  = (const float*)d_in[12];
    const float* eb1i  = (const float*)d_in[13];
    const float* eb1h  = (const float*)d_in[14];
    const float* mu_W  = (const float*)d_in[15];
    const float* mu_b  = (const float*)d_in[16];
    const float* lv_W  = (const float*)d_in[17];
    const float* lv_b  = (const float*)d_in[18];
    const float* dW0i  = (const float*)d_in[19];
    const float* dW0h  = (const float*)d_in[20];
    const float* db0i  = (const float*)d_in[21];
    const float* db0h  = (const float*)d_in[22];
    const float* dW1i  = (const float*)d_in[23];
    const float* dW1h  = (const float*)d_in[24];
    const float* db1i  = (const float*)d_in[25];
    const float* db1h  = (const float*)d_in[26];
    const float* postW = (const float*)d_in[27];
    const float* postb = (const float*)d_in[28];
    const float* postg = (const float*)d_in[29];
    const float* postbe= (const float*)d_in[30];
    const float* outW  = (const float*)d_in[31];
    const float* outb  = (const float*)d_in[32];

    char* ws = (char*)d_ws;
    uint16_t* XG   = (uint16_t*)(ws);                 // 65536*768*2 = 100663296 B
    uint16_t* YA   = (uint16_t*)(ws + 100663296);     // 33554432 B
    uint16_t* YB   = (uint16_t*)(ws + 134217728);     // 33554432 B
    float*    hlast= (float*)   (ws + 167772160);     // 524288 B
    float*    zbuf = (float*)   (ws + 168296448);     // 131072 B

    float* out    = (float*)d_out;
    float* mu_out = out + 4194304;
    float* lv_out = out + 4194304 + 32768;

    dim3 b256(256), b512(512);
    dim3 gxg(64, 4);

    k_inproj<<<1024, b256, 0, stream>>>(x, in_W, in_b, in_g, in_be, YA);
    k_xg<256,false><<<gxg, b512, 0, stream>>>(YA, eW0i, eb0i, XG, nullptr, nullptr);
    k_gru<<<256, b512, 0, stream>>>(XG, eW0h, eb0h, YB, nullptr);
    k_xg<256,false><<<gxg, b512, 0, stream>>>(YB, eW1i, eb1i, XG, nullptr, nullptr);
    k_gru<<<256, b512, 0, stream>>>(XG, eW1h, eb1h, nullptr, hlast);
    k_z<<<256, b256, 0, stream>>>(hlast, mu_W, mu_b, lv_W, lv_b, eps, mu_out, lv_out, zbuf);
    k_xg<64,true><<<gxg, b512, 0, stream>>>(nullptr, dW0i, db0i, XG, zbuf, dnz);
    k_gru<<<256, b512, 0, stream>>>(XG, dW0h, db0h, YA, nullptr);
    k_xg<256,false><<<gxg, b512, 0, stream>>>(YA, dW1i, db1i, XG, nullptr, nullptr);
    k_gru<<<256, b512, 0, stream>>>(XG, dW1h, db1h, YB, nullptr);
    k_post<<<1024, b256, 0, stream>>>(YB, postW, postb, postg, postbe, outW, outb, out);
}